// Round 1
// baseline (909.618 us; speedup 1.0000x reference)
//
#include <hip/hip_runtime.h>
#include <hip/hip_bf16.h>
#include <math.h>

typedef unsigned short u16;
typedef __attribute__((ext_vector_type(8))) short bf16x8;
typedef __attribute__((ext_vector_type(4))) float f32x4;

// ---------- helpers ----------
__device__ __forceinline__ u16 f2bf(float f) {
  union { float f; unsigned u; } x; x.f = f;
  unsigned r = x.u + 0x7fffu + ((x.u >> 16) & 1u);
  return (u16)(r >> 16);
}
__device__ __forceinline__ float bf2f(u16 h) {
  union { unsigned u; float f; } x; x.u = ((unsigned)h) << 16;
  return x.f;
}
__device__ __forceinline__ float sigmf(float x) {
  x = fminf(fmaxf(x, -30.f), 30.f);
  return 1.f / (1.f + __expf(-x));
}
__device__ __forceinline__ float tanh_fast(float x) {
  x = fminf(fmaxf(x, -15.f), 15.f);
  float t = __expf(2.f * x);
  return (t - 1.f) / (t + 1.f);
}

// ---------- problem constants ----------
#define NB 4
#define DE 128
#define DO_ 512
#define HW 1560
#define THW 6240
#define NP 1664   // HW padded to 13*128
#define KP 6272   // THW padded to 49*128
#define PROP 5

// ---------- generic bf16 GEMM:  C[M,N] = A[M,K] * Bt[N,K]^T  ----------
// A row-major [M,K] (ld=lda), Bt row-major [N,K] (ld=ldb). M=1664 always here.
// 128x128 tile, BK=32, 4 waves, 16x16x32 bf16 MFMA, global_load_lds staging.
#define BM 128
#define BN 128
#define BK 32

template<int MODE>
__global__ __launch_bounds__(256)
void gemm_bt(const u16* __restrict__ A, const u16* __restrict__ Bt,
             int K, int lda, int ldb, long a_bs, long b_bs,
             float* __restrict__ out0, long o0_bs, int ld0,
             u16* __restrict__ out1, long o1_bs, int ld1,
             const float* __restrict__ e0, long e0_bs,
             const float* __restrict__ e1, long e1_bs,
             const float* __restrict__ e2, long e2_bs,
             int nvalid, float scale)
{
  __shared__ u16 lds[8192];   // A: chunks 0..511 = [kg][row][8], B: 512..1023
  const int tid = threadIdx.x;
  const int wave = tid >> 6, lane = tid & 63;
  const int kg = lane >> 4, lr = lane & 15;
  const int wrw = wave >> 1, wcw = wave & 1;
  const long b = blockIdx.z;
  const int m0 = blockIdx.x * BM, n0 = blockIdx.y * BN;
  A += b * a_bs; Bt += b * b_bs;

  f32x4 acc[4][4];
#pragma unroll
  for (int m = 0; m < 4; ++m)
#pragma unroll
    for (int n = 0; n < 4; ++n) acc[m][n] = (f32x4){0.f, 0.f, 0.f, 0.f};

  for (int kt = 0; kt < K; kt += BK) {
#pragma unroll
    for (int i = 0; i < 4; ++i) {
      int c = tid + 256 * i;
      int cc = c & 511, row = cc & 127, g = cc >> 7;
      const u16* src = (i < 2) ? (A + (long)(m0 + row) * lda + kt + g * 8)
                               : (Bt + (long)(n0 + row) * ldb + kt + g * 8);
      __builtin_amdgcn_global_load_lds(
          (const __attribute__((address_space(1))) void*)src,
          (__attribute__((address_space(3))) void*)&lds[(wave * 64 + 256 * i) * 8],
          16, 0, 0);
    }
    __syncthreads();
    bf16x8 af[4], bfr[4];
#pragma unroll
    for (int m = 0; m < 4; ++m)
      af[m] = *(const bf16x8*)&lds[(kg * 128 + wrw * 64 + m * 16 + lr) * 8];
#pragma unroll
    for (int n = 0; n < 4; ++n)
      bfr[n] = *(const bf16x8*)&lds[(512 + kg * 128 + wcw * 64 + n * 16 + lr) * 8];
#pragma unroll
    for (int m = 0; m < 4; ++m)
#pragma unroll
      for (int n = 0; n < 4; ++n)
        acc[m][n] = __builtin_amdgcn_mfma_f32_16x16x32_bf16(af[m], bfr[n], acc[m][n], 0, 0, 0);
    __syncthreads();
  }

  // epilogue: frag elem j -> row = m0+wrw*64+m*16+kg*4+j, col = n0+wcw*64+n*16+lr
#pragma unroll
  for (int m = 0; m < 4; ++m) {
    int rloc = wrw * 64 + m * 16 + kg * 4;
#pragma unroll
    for (int n = 0; n < 4; ++n) {
      int col = n0 + wcw * 64 + n * 16 + lr;
#pragma unroll
      for (int j = 0; j < 4; ++j) {
        long row = m0 + rloc + j;
        float v = acc[m][n][j];
        if (MODE == 0) {            // scores -> Pt = exp(S/sqrt(De)), zero padded k
          float p = __expf(v * scale);
          out1[b * o1_bs + row * ld1 + col] = (col < nvalid) ? f2bf(p) : (u16)0;
        } else if (MODE == 1) {     // mem = (Pt @ m_out^T) * invZ[q]; write f32+bf16
          float val = v * e0[b * e0_bs + row];
          out0[b * o0_bs + row * ld0 + col] = val;
          out1[b * o1_bs + row * ld1 + col] = f2bf(val);
        } else if (MODE == 2) {     // Chru = memT @ Wruh^T + bias_ru
          out0[b * o0_bs + row * ld0 + col] = v + e0[col];
        } else if (MODE == 3) {     // gates r,u
          float gt = sigmf(v + e0[b * e0_bs + row * 1024 + col]);
          if (col < 512)            // r -> RH = r*mem (bf16) into XR cols 512..1023
            out1[b * o1_bs + row * ld1 + 512 + col] =
                f2bf(gt * e1[b * e1_bs + row * 512 + col]);
          else                      // u -> U (f32)
            out0[b * o0_bs + row * ld0 + (col - 512)] = gt;
        } else if (MODE == 4) {     // candidate + GRU update
          float cg = tanh_fast(v + e0[col]);
          float u = e1[b * e1_bs + row * 512 + col];
          float mm = e2[b * e2_bs + row * 512 + col];
          float x = mm * (1.f - u) + u * cg;
          out1[b * o1_bs + row * ld1 + col] = f2bf(x);
          if (out0) out0[b * o0_bs + row * ld0 + col] = x;
        }
      }
    }
  }
}

// ---------- small kernels ----------
// transpose+cast: in f32 [R][C] -> out bf16 [Cp][out_ld], out[c][r] = in[r][c], pad 0
__global__ void k_transpose_cast(const float* __restrict__ in, u16* __restrict__ out,
                                 int R, int C, int Cp, int out_ld,
                                 long in_bs, long out_bs) {
  __shared__ float t[32][33];
  long b = blockIdx.z;
  int c0 = blockIdx.x * 32, r0 = blockIdx.y * 32;
  int tx = threadIdx.x, ty = threadIdx.y;
#pragma unroll
  for (int i = 0; i < 32; i += 8) {
    int r = r0 + ty + i, c = c0 + tx;
    t[ty + i][tx] = (r < R && c < C) ? in[b * in_bs + (long)r * C + c] : 0.f;
  }
  __syncthreads();
#pragma unroll
  for (int i = 0; i < 32; i += 8) {
    int c = c0 + ty + i, r = r0 + tx;
    if (c < Cp && r < R)
      out[b * out_bs + (long)c * out_ld + r] = f2bf(t[tx][ty + i]);
  }
}

// cast f32 [R][Cin] -> bf16 [R][Cout] with zero pad
__global__ void k_cast_pad(const float* __restrict__ in, u16* __restrict__ out,
                           int Cin, int Cout, long in_bs, long out_bs) {
  int c = blockIdx.x * 256 + threadIdx.x;
  int r = blockIdx.y;
  long b = blockIdx.z;
  if (c >= Cout) return;
  out[b * out_bs + (long)r * Cout + c] =
      (c < Cin) ? f2bf(in[b * in_bs + (long)r * Cin + c]) : (u16)0;
}

__global__ void k_build_wru(const float* __restrict__ wr_, const float* __restrict__ wu_,
                            u16* __restrict__ wrux, u16* __restrict__ wruh) {
  int k = blockIdx.x * 256 + threadIdx.x;  // 0..511
  int m = blockIdx.y;                      // 0..1023
  if (k >= 512) return;
  const float* src = (m < 512) ? wr_ : wu_;
  int mm = m & 511;
  wrux[m * 512 + k] = f2bf(src[mm * 1024 + k]);
  wruh[m * 512 + k] = f2bf(src[mm * 1024 + 512 + k]);
}

__global__ void k_bias_ru(const float* __restrict__ br_, const float* __restrict__ bu_,
                          float* __restrict__ bias) {
  int i = blockIdx.x * 256 + threadIdx.x;
  if (i < 1024) bias[i] = (i < 512) ? br_[i] : bu_[i - 512];
}

// invZ[q] = 1 / sum_k Pt[q][k]
__global__ void k_colsum(const u16* __restrict__ Pt, float* __restrict__ invZ) {
  int q = blockIdx.x;
  long b = blockIdx.y;
  const u16* row = Pt + b * ((long)NP * KP) + (long)q * KP;
  float s = 0.f;
  for (int k = threadIdx.x; k < KP; k += 256) s += bf2f(row[k]);
  for (int o = 32; o > 0; o >>= 1) s += __shfl_down(s, o, 64);
  __shared__ float red[4];
  if ((threadIdx.x & 63) == 0) red[threadIdx.x >> 6] = s;
  __syncthreads();
  if (threadIdx.x == 0)
    invZ[b * NP + q] = 1.f / (red[0] + red[1] + red[2] + red[3]);
}

// Qfin [NP][512] f32 -> d_out[b][ch][HW] (first 512 channels)
__global__ void k_out_q(const float* __restrict__ Qfin, float* __restrict__ dout) {
  __shared__ float t[32][33];
  long b = blockIdx.z;
  int q0 = blockIdx.x * 32, ch0 = blockIdx.y * 32;
  int tx = threadIdx.x, ty = threadIdx.y;
#pragma unroll
  for (int i = 0; i < 32; i += 8)
    t[ty + i][tx] = Qfin[b * ((long)NP * 512) + (long)(q0 + ty + i) * 512 + ch0 + tx];
  __syncthreads();
#pragma unroll
  for (int i = 0; i < 32; i += 8) {
    int ch = ch0 + ty + i, q = q0 + tx;
    if (q < HW)
      dout[b * ((long)1024 * HW) + (long)ch * HW + q] = t[tx][ty + i];
  }
}

__global__ void k_copy_q0(const float4* __restrict__ src, float4* __restrict__ dst) {
  int idx = blockIdx.x * 256 + threadIdx.x;
  long b = blockIdx.z;
  const long n4 = (long)DO_ * HW / 4;  // 199680
  if (idx < n4)
    dst[b * ((long)1024 * HW / 4) + n4 + idx] = src[b * n4 + idx];
}

// ---------- host ----------
extern "C" void kernel_launch(void* const* d_in, const int* in_sizes, int n_in,
                              void* d_out, int out_size, void* d_ws, size_t ws_size,
                              hipStream_t stream) {
  const float* m_in  = (const float*)d_in[0];
  const float* m_out = (const float*)d_in[1];
  const float* q_in  = (const float*)d_in[2];
  const float* q_out = (const float*)d_in[3];
  const float* wr    = (const float*)d_in[4];
  const float* br    = (const float*)d_in[5];
  const float* wu    = (const float*)d_in[6];
  const float* bu    = (const float*)d_in[7];
  const float* wc    = (const float*)d_in[8];
  const float* bc    = (const float*)d_in[9];
  float* dout = (float*)d_out;

  // workspace layout (all sizes 256B-multiples)
  char* p = (char*)d_ws;
  size_t off = 0;
  auto alloc = [&](size_t bytes) { void* r = p + off; off += (bytes + 255) & ~(size_t)255; return r; };
  u16*   miT    = (u16*)alloc((size_t)NB * KP * DE * 2);       // [b][k(6272)][d(128)]
  u16*   qiT    = (u16*)alloc((size_t)NB * NP * DE * 2);       // [b][q(1664)][d(128)]
  u16*   Pt     = (u16*)alloc((size_t)NB * NP * KP * 2);       // [b][q][k] = exp(S)
  float* invZ   = (float*)alloc((size_t)NB * NP * 4);
  u16*   moutb  = (u16*)alloc((size_t)NB * DO_ * KP * 2);      // [b][o][k]
  float* memTf  = (float*)alloc((size_t)NB * NP * DO_ * 4);    // [b][q][o]
  u16*   memTb  = (u16*)alloc((size_t)NB * NP * DO_ * 2);
  float* chru   = (float*)alloc((size_t)NB * NP * 1024 * 4);   // [b][q][1024]
  float* U      = (float*)alloc((size_t)NB * NP * DO_ * 4);
  u16*   XRa    = (u16*)alloc((size_t)NB * NP * 1024 * 2);     // [b][q][x(512)|rh(512)]
  u16*   XRb    = (u16*)alloc((size_t)NB * NP * 1024 * 2);
  float* Qfin   = (float*)alloc((size_t)NB * NP * DO_ * 4);
  u16*   wrux   = (u16*)alloc((size_t)1024 * 512 * 2);
  u16*   wruh   = (u16*)alloc((size_t)1024 * 512 * 2);
  u16*   wcb    = (u16*)alloc((size_t)512 * 1024 * 2);
  float* biasru = (float*)alloc((size_t)1024 * 4);
  if (off > ws_size) return;  // workspace too small -> fail visibly

  // --- prep: weights ---
  k_build_wru<<<dim3(2, 1024), 256, 0, stream>>>(wr, wu, wrux, wruh);
  k_cast_pad<<<dim3(4, 512, 1), 256, 0, stream>>>(wc, wcb, 1024, 1024, 0, 0);
  k_bias_ru<<<dim3(4), 256, 0, stream>>>(br, bu, biasru);
  // --- prep: inputs ---
  k_cast_pad<<<dim3(25, 512, NB), 256, 0, stream>>>(
      m_out, moutb, THW, KP, (long)DO_ * THW, (long)DO_ * KP);
  k_transpose_cast<<<dim3(196, 4, NB), dim3(32, 8), 0, stream>>>(
      m_in, miT, DE, THW, KP, DE, (long)DE * THW, (long)KP * DE);
  k_transpose_cast<<<dim3(52, 4, NB), dim3(32, 8), 0, stream>>>(
      q_in, qiT, DE, HW, NP, DE, (long)DE * HW, (long)NP * DE);
  k_transpose_cast<<<dim3(52, 16, NB), dim3(32, 8), 0, stream>>>(
      q_out, XRa, DO_, HW, NP, 1024, (long)DO_ * HW, (long)NP * 1024);

  // --- attention scores: Pt[q,k] = exp(qiT·miT^T / sqrt(De)) ---
  gemm_bt<0><<<dim3(13, 49, NB), 256, 0, stream>>>(
      qiT, miT, DE, DE, DE, (long)NP * DE, (long)KP * DE,
      nullptr, 0, 0, Pt, (long)NP * KP, KP,
      nullptr, 0, nullptr, 0, nullptr, 0, THW, 0.08838834764831845f);
  k_colsum<<<dim3(NP, NB), 256, 0, stream>>>(Pt, invZ);

  // --- mem: memT[q,o] = (Pt @ moutb^T) * invZ ---
  gemm_bt<1><<<dim3(13, 4, NB), 256, 0, stream>>>(
      Pt, moutb, KP, KP, KP, (long)NP * KP, (long)DO_ * KP,
      memTf, (long)NP * DO_, DO_, memTb, (long)NP * DO_, DO_,
      invZ, NP, nullptr, 0, nullptr, 0, 0, 0.f);

  // --- Chru = memT @ Wruh^T + [br;bu] ---
  gemm_bt<2><<<dim3(13, 8, NB), 256, 0, stream>>>(
      memTb, wruh, DO_, DO_, DO_, (long)NP * DO_, 0,
      chru, (long)NP * 1024, 1024, nullptr, 0, 0,
      biasru, 0, nullptr, 0, nullptr, 0, 0, 0.f);

  // --- GRU layers ---
  u16* xr[2] = {XRa, XRb};
  for (int l = 0; l < PROP; ++l) {
    u16* cur = xr[l & 1];
    u16* nxt = xr[(l + 1) & 1];
    // gates r,u: sigmoid(X @ Wrux^T + Chru); r*mem -> cur cols 512.., u -> U
    gemm_bt<3><<<dim3(13, 8, NB), 256, 0, stream>>>(
        cur, wrux, DO_, 1024, DO_, (long)NP * 1024, 0,
        U, (long)NP * DO_, DO_, cur, (long)NP * 1024, 1024,
        chru, (long)NP * 1024, memTf, (long)NP * DO_, nullptr, 0, 0, 0.f);
    // candidate + update: x' = mem*(1-u) + u*tanh(XR @ wc^T + bc)
    gemm_bt<4><<<dim3(13, 4, NB), 256, 0, stream>>>(
        cur, wcb, 1024, 1024, 1024, (long)NP * 1024, 0,
        (l == PROP - 1) ? Qfin : nullptr, (long)NP * DO_, DO_,
        nxt, (long)NP * 1024, 1024,
        bc, 0, U, (long)NP * DO_, memTf, (long)NP * DO_, 0, 0.f);
  }

  // --- outputs ---
  k_out_q<<<dim3(49, 16, NB), dim3(32, 8), 0, stream>>>(Qfin, dout);
  k_copy_q0<<<dim3(780, 1, NB), 256, 0, stream>>>((const float4*)q_out, (float4*)dout);
}

// Round 2
// 856.752 us; speedup vs baseline: 1.0617x; 1.0617x over previous
//
#include <hip/hip_runtime.h>
#include <hip/hip_bf16.h>
#include <math.h>

typedef unsigned short u16;
typedef __attribute__((ext_vector_type(8))) short bf16x8;
typedef __attribute__((ext_vector_type(4))) float f32x4;

// ---------- helpers ----------
__device__ __forceinline__ u16 f2bf(float f) {
  union { float f; unsigned u; } x; x.f = f;
  unsigned r = x.u + 0x7fffu + ((x.u >> 16) & 1u);
  return (u16)(r >> 16);
}
__device__ __forceinline__ float bf2f(u16 h) {
  union { unsigned u; float f; } x; x.u = ((unsigned)h) << 16;
  return x.f;
}
__device__ __forceinline__ float sigmf(float x) {
  x = fminf(fmaxf(x, -30.f), 30.f);
  return 1.f / (1.f + __expf(-x));
}
__device__ __forceinline__ float tanh_fast(float x) {
  x = fminf(fmaxf(x, -15.f), 15.f);
  float t = __expf(2.f * x);
  return (t - 1.f) / (t + 1.f);
}

// ---------- problem constants ----------
#define NB 4
#define DE 128
#define DO_ 512
#define HW 1560
#define THW 6240
#define NP 1664   // HW padded to 13*128
#define KP 6272   // THW padded to 49*128
#define PROP 5

// ---------- generic bf16 GEMM:  C[M,N] = A[M,K] * Bt[N,K]^T  ----------
// A row-major [M,K] (ld=lda), Bt row-major [N,K] (ld=ldb).
// 128x128 tile, BK=32, 4 waves, 16x16x32 bf16 MFMA, global_load_lds staging.
// SPLIT>1: K split into SPLIT chunks; blockIdx.z = b*SPLIT + chunk; MODE 5
// writes raw f32 partials indexed by blockIdx.z.
#define BM 128
#define BN 128
#define BK 32

template<int MODE, int SPLIT = 1>
__global__ __launch_bounds__(256)
void gemm_bt(const u16* __restrict__ A, const u16* __restrict__ Bt,
             int K, int lda, int ldb, long a_bs, long b_bs,
             float* __restrict__ out0, long o0_bs, int ld0,
             u16* __restrict__ out1, long o1_bs, int ld1,
             const float* __restrict__ e0, long e0_bs,
             const float* __restrict__ e1, long e1_bs,
             const float* __restrict__ e2, long e2_bs,
             int nvalid, float scale)
{
  __shared__ u16 lds[8192];   // A: chunks 0..511 = [kg][row][8], B: 512..1023
  const int tid = threadIdx.x;
  const int wave = tid >> 6, lane = tid & 63;
  const int kg = lane >> 4, lr = lane & 15;
  const int wrw = wave >> 1, wcw = wave & 1;
  const int z = blockIdx.z;
  const long b = (SPLIT > 1) ? (z / SPLIT) : z;
  const int ks = K / SPLIT;
  const int k0 = (SPLIT > 1) ? (z % SPLIT) * ks : 0;
  const int m0 = blockIdx.x * BM, n0 = blockIdx.y * BN;
  A += b * a_bs; Bt += b * b_bs;

  f32x4 acc[4][4];
#pragma unroll
  for (int m = 0; m < 4; ++m)
#pragma unroll
    for (int n = 0; n < 4; ++n) acc[m][n] = (f32x4){0.f, 0.f, 0.f, 0.f};

  for (int kt = k0; kt < k0 + ks; kt += BK) {
#pragma unroll
    for (int i = 0; i < 4; ++i) {
      int c = tid + 256 * i;
      int cc = c & 511, row = cc & 127, g = cc >> 7;
      const u16* src = (i < 2) ? (A + (long)(m0 + row) * lda + kt + g * 8)
                               : (Bt + (long)(n0 + row) * ldb + kt + g * 8);
      __builtin_amdgcn_global_load_lds(
          (const __attribute__((address_space(1))) void*)src,
          (__attribute__((address_space(3))) void*)&lds[(wave * 64 + 256 * i) * 8],
          16, 0, 0);
    }
    __syncthreads();
    bf16x8 af[4], bfr[4];
#pragma unroll
    for (int m = 0; m < 4; ++m)
      af[m] = *(const bf16x8*)&lds[(kg * 128 + wrw * 64 + m * 16 + lr) * 8];
#pragma unroll
    for (int n = 0; n < 4; ++n)
      bfr[n] = *(const bf16x8*)&lds[(512 + kg * 128 + wcw * 64 + n * 16 + lr) * 8];
#pragma unroll
    for (int m = 0; m < 4; ++m)
#pragma unroll
      for (int n = 0; n < 4; ++n)
        acc[m][n] = __builtin_amdgcn_mfma_f32_16x16x32_bf16(af[m], bfr[n], acc[m][n], 0, 0, 0);
    __syncthreads();
  }

  // frag elem j -> row = m0+wrw*64+m*16+kg*4+j, col = n0+wcw*64+n*16+lr
  if (MODE == 0) {
    // scores -> Pt = exp(S*scale), zero padded k; also per-block row-sums Zp
    float rs[4][4];
#pragma unroll
    for (int m = 0; m < 4; ++m)
#pragma unroll
      for (int j = 0; j < 4; ++j) rs[m][j] = 0.f;
#pragma unroll
    for (int m = 0; m < 4; ++m) {
      int rloc = wrw * 64 + m * 16 + kg * 4;
#pragma unroll
      for (int n = 0; n < 4; ++n) {
        int col = n0 + wcw * 64 + n * 16 + lr;
#pragma unroll
        for (int j = 0; j < 4; ++j) {
          long row = m0 + rloc + j;
          float p = __expf(acc[m][n][j] * scale);
          bool valid = (col < nvalid);
          out1[b * o1_bs + row * ld1 + col] = valid ? f2bf(p) : (u16)0;
          rs[m][j] += valid ? p : 0.f;
        }
      }
    }
    // reduce over lr (16 lanes; xor masks 1,2,4,8 stay within kg group)
#pragma unroll
    for (int m = 0; m < 4; ++m)
#pragma unroll
      for (int j = 0; j < 4; ++j) {
#pragma unroll
        for (int msk = 1; msk < 16; msk <<= 1)
          rs[m][j] += __shfl_xor(rs[m][j], msk, 64);
      }
    float* zbuf = (float*)lds;  // 2*128 floats
    if (lr == 0) {
#pragma unroll
      for (int m = 0; m < 4; ++m)
#pragma unroll
        for (int j = 0; j < 4; ++j)
          zbuf[wcw * 128 + wrw * 64 + m * 16 + kg * 4 + j] = rs[m][j];
    }
    __syncthreads();
    if (tid < 128)
      out0[b * o0_bs + (long)blockIdx.y * NP + (m0 + tid)] = zbuf[tid] + zbuf[128 + tid];
    return;
  }

#pragma unroll
  for (int m = 0; m < 4; ++m) {
    int rloc = wrw * 64 + m * 16 + kg * 4;
#pragma unroll
    for (int n = 0; n < 4; ++n) {
      int col = n0 + wcw * 64 + n * 16 + lr;
#pragma unroll
      for (int j = 0; j < 4; ++j) {
        long row = m0 + rloc + j;
        float v = acc[m][n][j];
        if (MODE == 5) {            // split-K raw partial
          out0[(long)z * o0_bs + row * ld0 + col] = v;
        } else if (MODE == 2) {     // Chru = memT @ Wruh^T + bias_ru
          out0[b * o0_bs + row * ld0 + col] = v + e0[col];
        } else if (MODE == 3) {     // gates r,u
          float gt = sigmf(v + e0[b * e0_bs + row * 1024 + col]);
          if (col < 512)            // r -> RH = r*mem (bf16) into XR cols 512..1023
            out1[b * o1_bs + row * ld1 + 512 + col] =
                f2bf(gt * e1[b * e1_bs + row * 512 + col]);
          else                      // u -> U (f32)
            out0[b * o0_bs + row * ld0 + (col - 512)] = gt;
        } else if (MODE == 4) {     // candidate + GRU update
          float cg = tanh_fast(v + e0[col]);
          float u = e1[b * e1_bs + row * 512 + col];
          float mm = e2[b * e2_bs + row * 512 + col];
          float x = mm * (1.f - u) + u * cg;
          out1[b * o1_bs + row * ld1 + col] = f2bf(x);
          if (out0) out0[b * o0_bs + row * ld0 + col] = x;
        }
      }
    }
  }
}

// ---------- small kernels ----------
// transpose+cast: in f32 [R][C] -> out bf16 [Cp][out_ld], out[c][r] = in[r][c], pad 0
__global__ void k_transpose_cast(const float* __restrict__ in, u16* __restrict__ out,
                                 int R, int C, int Cp, int out_ld,
                                 long in_bs, long out_bs) {
  __shared__ float t[32][33];
  long b = blockIdx.z;
  int c0 = blockIdx.x * 32, r0 = blockIdx.y * 32;
  int tx = threadIdx.x, ty = threadIdx.y;
#pragma unroll
  for (int i = 0; i < 32; i += 8) {
    int r = r0 + ty + i, c = c0 + tx;
    t[ty + i][tx] = (r < R && c < C) ? in[b * in_bs + (long)r * C + c] : 0.f;
  }
  __syncthreads();
#pragma unroll
  for (int i = 0; i < 32; i += 8) {
    int c = c0 + ty + i, r = r0 + tx;
    if (c < Cp && r < R)
      out[b * out_bs + (long)c * out_ld + r] = f2bf(t[tx][ty + i]);
  }
}

// cast f32 [R][Cin] -> bf16 [R][Cout] with zero pad
__global__ void k_cast_pad(const float* __restrict__ in, u16* __restrict__ out,
                           int Cin, int Cout, long in_bs, long out_bs) {
  int c = blockIdx.x * 256 + threadIdx.x;
  int r = blockIdx.y;
  long b = blockIdx.z;
  if (c >= Cout) return;
  out[b * out_bs + (long)r * Cout + c] =
      (c < Cin) ? f2bf(in[b * in_bs + (long)r * Cin + c]) : (u16)0;
}

__global__ void k_build_wru(const float* __restrict__ wr_, const float* __restrict__ wu_,
                            u16* __restrict__ wrux, u16* __restrict__ wruh) {
  int k = blockIdx.x * 256 + threadIdx.x;  // 0..511
  int m = blockIdx.y;                      // 0..1023
  if (k >= 512) return;
  const float* src = (m < 512) ? wr_ : wu_;
  int mm = m & 511;
  wrux[m * 512 + k] = f2bf(src[mm * 1024 + k]);
  wruh[m * 512 + k] = f2bf(src[mm * 1024 + 512 + k]);
}

__global__ void k_bias_ru(const float* __restrict__ br_, const float* __restrict__ bu_,
                          float* __restrict__ bias) {
  int i = blockIdx.x * 256 + threadIdx.x;
  if (i < 1024) bias[i] = (i < 512) ? br_[i] : bu_[i - 512];
}

// invZ[b][q] = 1 / sum_nb Zp[b][nb][q]
__global__ void k_invz(const float* __restrict__ Zp, float* __restrict__ invZ) {
  int t = blockIdx.x * 256 + threadIdx.x;
  if (t >= NB * NP) return;
  int b = t / NP, q = t - b * NP;
  const float* base = Zp + (long)b * 49 * NP + q;
  float s = 0.f;
#pragma unroll
  for (int nb = 0; nb < 49; ++nb) s += base[(long)nb * NP];
  invZ[t] = 1.f / s;
}

// memT[b][q][o] = invZ[b][q] * sum_s Ppart[b*4+s][q][o]; write f32 + bf16
__global__ void k_reduce_mem(const float* __restrict__ Ppart, const float* __restrict__ invZ,
                             float* __restrict__ memTf, u16* __restrict__ memTb) {
  long t = (long)blockIdx.x * 256 + threadIdx.x;   // f32x4 index
  const long bs = (long)NP * DO_;
  if (t >= (long)NB * bs / 4) return;
  long flat = t * 4;
  int b = (int)(flat / bs);
  long r = flat - (long)b * bs;
  int q = (int)(r / DO_);
  f32x4 s = (f32x4){0.f, 0.f, 0.f, 0.f};
#pragma unroll
  for (int sp = 0; sp < 4; ++sp)
    s += *(const f32x4*)&Ppart[(long)(b * 4 + sp) * bs + r];
  float iz = invZ[b * NP + q];
  s *= iz;
  *(f32x4*)&memTf[(long)b * bs + r] = s;
  uint2 pk;
  pk.x = (unsigned)f2bf(s[0]) | ((unsigned)f2bf(s[1]) << 16);
  pk.y = (unsigned)f2bf(s[2]) | ((unsigned)f2bf(s[3]) << 16);
  *(uint2*)&memTb[(long)b * bs + r] = pk;
}

// Qfin [NP][512] f32 -> d_out[b][ch][HW] (first 512 channels)
__global__ void k_out_q(const float* __restrict__ Qfin, float* __restrict__ dout) {
  __shared__ float t[32][33];
  long b = blockIdx.z;
  int q0 = blockIdx.x * 32, ch0 = blockIdx.y * 32;
  int tx = threadIdx.x, ty = threadIdx.y;
#pragma unroll
  for (int i = 0; i < 32; i += 8)
    t[ty + i][tx] = Qfin[b * ((long)NP * 512) + (long)(q0 + ty + i) * 512 + ch0 + tx];
  __syncthreads();
#pragma unroll
  for (int i = 0; i < 32; i += 8) {
    int ch = ch0 + ty + i, q = q0 + tx;
    if (q < HW)
      dout[b * ((long)1024 * HW) + (long)ch * HW + q] = t[tx][ty + i];
  }
}

__global__ void k_copy_q0(const float4* __restrict__ src, float4* __restrict__ dst) {
  int idx = blockIdx.x * 256 + threadIdx.x;
  long b = blockIdx.z;
  const long n4 = (long)DO_ * HW / 4;  // 199680
  if (idx < n4)
    dst[b * ((long)1024 * HW / 4) + n4 + idx] = src[b * n4 + idx];
}

// ---------- host ----------
extern "C" void kernel_launch(void* const* d_in, const int* in_sizes, int n_in,
                              void* d_out, int out_size, void* d_ws, size_t ws_size,
                              hipStream_t stream) {
  const float* m_in  = (const float*)d_in[0];
  const float* m_out = (const float*)d_in[1];
  const float* q_in  = (const float*)d_in[2];
  const float* q_out = (const float*)d_in[3];
  const float* wr    = (const float*)d_in[4];
  const float* br    = (const float*)d_in[5];
  const float* wu    = (const float*)d_in[6];
  const float* bu    = (const float*)d_in[7];
  const float* wc    = (const float*)d_in[8];
  const float* bc    = (const float*)d_in[9];
  float* dout = (float*)d_out;

  // workspace layout (all sizes 256B-multiples)
  char* p = (char*)d_ws;
  size_t off = 0;
  auto alloc = [&](size_t bytes) { void* r = p + off; off += (bytes + 255) & ~(size_t)255; return r; };
  u16*   miT    = (u16*)alloc((size_t)NB * KP * DE * 2);       // [b][k(6272)][d(128)]
  u16*   qiT    = (u16*)alloc((size_t)NB * NP * DE * 2);       // [b][q(1664)][d(128)]
  u16*   Pt     = (u16*)alloc((size_t)NB * NP * KP * 2);       // [b][q][k] = exp(S)
  float* invZ   = (float*)alloc((size_t)NB * NP * 4);
  u16*   moutb  = (u16*)alloc((size_t)NB * DO_ * KP * 2);      // [b][o][k]
  float* memTf  = (float*)alloc((size_t)NB * NP * DO_ * 4);    // [b][q][o]
  u16*   memTb  = (u16*)alloc((size_t)NB * NP * DO_ * 2);
  // chru, U, XRb are contiguous; split-K partials alias this span (dead before
  // any of the three is written):  4 splits * NB*NP*DO_*4 B = 54,525,952 B
  float* chru   = (float*)alloc((size_t)NB * NP * 1024 * 4);   // [b][q][1024]
  float* U      = (float*)alloc((size_t)NB * NP * DO_ * 4);
  u16*   XRb    = (u16*)alloc((size_t)NB * NP * 1024 * 2);
  u16*   XRa    = (u16*)alloc((size_t)NB * NP * 1024 * 2);     // [b][q][x(512)|rh(512)]
  float* Qfin   = (float*)alloc((size_t)NB * NP * DO_ * 4);
  u16*   wrux   = (u16*)alloc((size_t)1024 * 512 * 2);
  u16*   wruh   = (u16*)alloc((size_t)1024 * 512 * 2);
  u16*   wcb    = (u16*)alloc((size_t)512 * 1024 * 2);
  float* biasru = (float*)alloc((size_t)1024 * 4);
  float* Ppart  = (float*)chru;    // [16][NP][DO_] f32, alias
  float* Zp     = (float*)memTb;   // [NB][49][NP] f32, alias (dead before memTb write)
  if (off > ws_size) return;  // workspace too small -> fail visibly

  // --- prep: weights ---
  k_build_wru<<<dim3(2, 1024), 256, 0, stream>>>(wr, wu, wrux, wruh);
  k_cast_pad<<<dim3(4, 512, 1), 256, 0, stream>>>(wc, wcb, 1024, 1024, 0, 0);
  k_bias_ru<<<dim3(4), 256, 0, stream>>>(br, bu, biasru);
  // --- prep: inputs ---
  k_cast_pad<<<dim3(25, 512, NB), 256, 0, stream>>>(
      m_out, moutb, THW, KP, (long)DO_ * THW, (long)DO_ * KP);
  k_transpose_cast<<<dim3(196, 4, NB), dim3(32, 8), 0, stream>>>(
      m_in, miT, DE, THW, KP, DE, (long)DE * THW, (long)KP * DE);
  k_transpose_cast<<<dim3(52, 4, NB), dim3(32, 8), 0, stream>>>(
      q_in, qiT, DE, HW, NP, DE, (long)DE * HW, (long)NP * DE);
  k_transpose_cast<<<dim3(52, 16, NB), dim3(32, 8), 0, stream>>>(
      q_out, XRa, DO_, HW, NP, 1024, (long)DO_ * HW, (long)NP * 1024);

  // --- attention scores: Pt[q,k] = exp(qiT·miT^T / sqrt(De)); Zp row-partials ---
  gemm_bt<0><<<dim3(13, 49, NB), 256, 0, stream>>>(
      qiT, miT, DE, DE, DE, (long)NP * DE, (long)KP * DE,
      Zp, (long)49 * NP, 0, Pt, (long)NP * KP, KP,
      nullptr, 0, nullptr, 0, nullptr, 0, THW, 0.08838834764831845f);
  k_invz<<<dim3(26), 256, 0, stream>>>(Zp, invZ);

  // --- mem (split-K x4): Ppart[z] = Pt @ moutb^T chunk; then reduce*invZ ---
  gemm_bt<5, 4><<<dim3(13, 4, NB * 4), 256, 0, stream>>>(
      Pt, moutb, KP, KP, KP, (long)NP * KP, (long)DO_ * KP,
      Ppart, (long)NP * DO_, DO_, nullptr, 0, 0,
      nullptr, 0, nullptr, 0, nullptr, 0, 0, 0.f);
  k_reduce_mem<<<dim3(3328), 256, 0, stream>>>(Ppart, invZ, memTf, memTb);

  // --- Chru = memT @ Wruh^T + [br;bu] ---
  gemm_bt<2><<<dim3(13, 8, NB), 256, 0, stream>>>(
      memTb, wruh, DO_, DO_, DO_, (long)NP * DO_, 0,
      chru, (long)NP * 1024, 1024, nullptr, 0, 0,
      biasru, 0, nullptr, 0, nullptr, 0, 0, 0.f);

  // --- GRU layers ---
  u16* xr[2] = {XRa, XRb};
  for (int l = 0; l < PROP; ++l) {
    u16* cur = xr[l & 1];
    u16* nxt = xr[(l + 1) & 1];
    // gates r,u: sigmoid(X @ Wrux^T + Chru); r*mem -> cur cols 512.., u -> U
    gemm_bt<3><<<dim3(13, 8, NB), 256, 0, stream>>>(
        cur, wrux, DO_, 1024, DO_, (long)NP * 1024, 0,
        U, (long)NP * DO_, DO_, cur, (long)NP * 1024, 1024,
        chru, (long)NP * 1024, memTf, (long)NP * DO_, nullptr, 0, 0, 0.f);
    // candidate + update: x' = mem*(1-u) + u*tanh(XR @ wc^T + bc)
    gemm_bt<4><<<dim3(13, 4, NB), 256, 0, stream>>>(
        cur, wcb, 1024, 1024, 1024, (long)NP * 1024, 0,
        (l == PROP - 1) ? Qfin : nullptr, (long)NP * DO_, DO_,
        nxt, (long)NP * 1024, 1024,
        bc, 0, U, (long)NP * DO_, memTf, (long)NP * DO_, 0, 0.f);
  }

  // --- outputs ---
  k_out_q<<<dim3(49, 16, NB), dim3(32, 8), 0, stream>>>(Qfin, dout);
  k_copy_q0<<<dim3(780, 1, NB), 256, 0, stream>>>((const float4*)q_out, (float4*)dout);
}

// Round 3
// 736.653 us; speedup vs baseline: 1.2348x; 1.1630x over previous
//
#include <hip/hip_runtime.h>
#include <hip/hip_bf16.h>
#include <math.h>

typedef unsigned short u16;
typedef __attribute__((ext_vector_type(8))) short bf16x8;
typedef __attribute__((ext_vector_type(4))) float f32x4;

// ---------- helpers ----------
__device__ __forceinline__ u16 f2bf(float f) {
  union { float f; unsigned u; } x; x.f = f;
  unsigned r = x.u + 0x7fffu + ((x.u >> 16) & 1u);
  return (u16)(r >> 16);
}
__device__ __forceinline__ float bf2f(u16 h) {
  union { unsigned u; float f; } x; x.u = ((unsigned)h) << 16;
  return x.f;
}
__device__ __forceinline__ float sigmf(float x) {
  x = fminf(fmaxf(x, -30.f), 30.f);
  return 1.f / (1.f + __expf(-x));
}
__device__ __forceinline__ float tanh_fast(float x) {
  x = fminf(fmaxf(x, -15.f), 15.f);
  float t = __expf(2.f * x);
  return (t - 1.f) / (t + 1.f);
}

// ---------- problem constants ----------
#define NB 4
#define DE 128
#define DO_ 512
#define HW 1560
#define THW 6240
#define NP 1664   // HW padded to 13*128
#define KP 6272   // THW padded to 49*128
#define PROP 5

// ---------- generic bf16 GEMM:  C[M,N] = A[M,K] * Bt[N,K]^T  ----------
// A row-major [M,K] (ld=lda), Bt row-major [N,K] (ld=ldb).
// Tile BMT x 128, BK=32, 4 waves, 16x16x32 bf16 MFMA, global_load_lds staging.
// BMT=128: 2x2 wave grid (acc 4x4); BMT=64: 1x4 wave grid (acc 4x2).
// SPLIT>1: blockIdx.z = b*SPLIT + chunk; MODE 5 writes f32 partials per z
// (already scaled by invZ).
#define BK 32

template<int MODE, int SPLIT, int BMT>
__global__ __launch_bounds__(256)
void gemm_bt(const u16* __restrict__ A, const u16* __restrict__ Bt,
             int K, int lda, int ldb, long a_bs, long b_bs,
             void* __restrict__ out0v, long o0_bs, int ld0,
             u16* __restrict__ out1, long o1_bs, int ld1,
             const void* __restrict__ e0v, long e0_bs,
             const void* __restrict__ e1v, long e1_bs,
             const void* __restrict__ e2v, long e2_bs,
             int nvalid, float scale)
{
  constexpr int WR = BMT / 64;        // wave rows (2 or 1)
  constexpr int WC = 4 / WR;          // wave cols (2 or 4)
  constexpr int NF = 8 / WC;          // 16-wide n-frags per wave (4 or 2)
  constexpr int ASLOT = BMT * 4;      // A 16B-slots
  constexpr int NISS = (ASLOT + 512) / 256;
  constexpr int RSH = (BMT == 128) ? 7 : 6;
  __shared__ u16 lds[(BMT + 128) * 32];

  const int tid = threadIdx.x;
  const int wave = tid >> 6, lane = tid & 63;
  const int kg = lane >> 4, lr = lane & 15;
  const int wrw = wave / WC, wcw = wave % WC;
  const int z = blockIdx.z;
  const long b = (SPLIT > 1) ? (z / SPLIT) : z;
  const int ks = K / SPLIT;
  const int k0 = (SPLIT > 1) ? (z % SPLIT) * ks : 0;
  const int m0 = blockIdx.x * BMT, n0 = blockIdx.y * 128;
  A += b * a_bs; Bt += b * b_bs;

  float* out0f = (float*)out0v;
  u16* out0h = (u16*)out0v;
  const float* e0f = (const float*)e0v;
  const u16* e0h = (const u16*)e0v;
  const u16* e1h = (const u16*)e1v;
  const u16* e2h = (const u16*)e2v;

  f32x4 acc[4][NF];
#pragma unroll
  for (int m = 0; m < 4; ++m)
#pragma unroll
    for (int n = 0; n < NF; ++n) acc[m][n] = (f32x4){0.f, 0.f, 0.f, 0.f};

  for (int kt = k0; kt < k0 + ks; kt += BK) {
#pragma unroll
    for (int i = 0; i < NISS; ++i) {
      int s = tid + 256 * i;
      const u16* src;
      if (s < ASLOT) {
        int row = s & (BMT - 1), g = s >> RSH;
        src = A + (long)(m0 + row) * lda + kt + g * 8;
      } else {
        int t = s - ASLOT;
        int row = t & 127, g = t >> 7;
        src = Bt + (long)(n0 + row) * ldb + kt + g * 8;
      }
      __builtin_amdgcn_global_load_lds(
          (const __attribute__((address_space(1))) void*)src,
          (__attribute__((address_space(3))) void*)&lds[(wave * 64 + 256 * i) * 8],
          16, 0, 0);
    }
    __syncthreads();
    bf16x8 af[4], bfr[NF];
#pragma unroll
    for (int m = 0; m < 4; ++m)
      af[m] = *(const bf16x8*)&lds[(kg * BMT + wrw * 64 + m * 16 + lr) * 8];
#pragma unroll
    for (int n = 0; n < NF; ++n)
      bfr[n] = *(const bf16x8*)&lds[(ASLOT + kg * 128 + (wcw * NF + n) * 16 + lr) * 8];
#pragma unroll
    for (int m = 0; m < 4; ++m)
#pragma unroll
      for (int n = 0; n < NF; ++n)
        acc[m][n] = __builtin_amdgcn_mfma_f32_16x16x32_bf16(af[m], bfr[n], acc[m][n], 0, 0, 0);
    __syncthreads();
  }

  // frag elem j -> row = m0+wrw*64+m*16+kg*4+j, col = n0+(wcw*NF+n)*16+lr
  if constexpr (MODE == 0) {
    // scores -> Pt = exp(S*scale), zero padded k; also per-block row-sums Zp
    float rs[4][4];
#pragma unroll
    for (int m = 0; m < 4; ++m)
#pragma unroll
      for (int j = 0; j < 4; ++j) rs[m][j] = 0.f;
#pragma unroll
    for (int m = 0; m < 4; ++m) {
      int rloc = wrw * 64 + m * 16 + kg * 4;
#pragma unroll
      for (int n = 0; n < NF; ++n) {
        int col = n0 + (wcw * NF + n) * 16 + lr;
#pragma unroll
        for (int j = 0; j < 4; ++j) {
          long row = m0 + rloc + j;
          float p = __expf(acc[m][n][j] * scale);
          bool valid = (col < nvalid);
          out1[b * o1_bs + row * ld1 + col] = valid ? f2bf(p) : (u16)0;
          rs[m][j] += valid ? p : 0.f;
        }
      }
    }
#pragma unroll
    for (int m = 0; m < 4; ++m)
#pragma unroll
      for (int j = 0; j < 4; ++j) {
#pragma unroll
        for (int msk = 1; msk < 16; msk <<= 1)
          rs[m][j] += __shfl_xor(rs[m][j], msk, 64);
      }
    float* zbuf = (float*)lds;  // 2*128 floats
    if (lr == 0) {
#pragma unroll
      for (int m = 0; m < 4; ++m)
#pragma unroll
        for (int j = 0; j < 4; ++j)
          zbuf[wcw * 128 + wrw * 64 + m * 16 + kg * 4 + j] = rs[m][j];
    }
    __syncthreads();
    if (tid < 128)
      out0f[b * o0_bs + (long)blockIdx.y * NP + (m0 + tid)] = zbuf[tid] + zbuf[128 + tid];
    return;
  }

#pragma unroll
  for (int m = 0; m < 4; ++m) {
    int rloc = wrw * 64 + m * 16 + kg * 4;
#pragma unroll
    for (int n = 0; n < NF; ++n) {
      int col = n0 + (wcw * NF + n) * 16 + lr;
#pragma unroll
      for (int j = 0; j < 4; ++j) {
        long row = m0 + rloc + j;
        float v = acc[m][n][j];
        if constexpr (MODE == 5) {        // split-K partial, pre-scaled by invZ
          out0f[(long)z * o0_bs + row * ld0 + col] = v * e0f[b * e0_bs + row];
        } else if constexpr (MODE == 2) { // Chru(bf16) = memT @ Wruh^T + bias_ru
          out1[b * o1_bs + row * ld1 + col] = f2bf(v + e0f[col]);
        } else if constexpr (MODE == 3) { // gates r,u (chru bf16, mem bf16)
          float gt = sigmf(v + bf2f(e0h[b * e0_bs + row * 1024 + col]));
          if (col < 512)                  // r -> RH = r*mem into XR cols 512..1023
            out1[b * o1_bs + row * ld1 + 512 + col] =
                f2bf(gt * bf2f(e1h[b * e1_bs + row * 512 + col]));
          else                            // u -> U (bf16)
            out0h[b * o0_bs + row * ld0 + (col - 512)] = f2bf(gt);
        } else if constexpr (MODE == 4) { // candidate + GRU update
          float cg = tanh_fast(v + e0f[col]);
          float u = bf2f(e1h[b * e1_bs + row * 512 + col]);
          float mm = bf2f(e2h[b * e2_bs + row * 512 + col]);
          float x = mm * (1.f - u) + u * cg;
          out1[b * o1_bs + row * ld1 + col] = f2bf(x);
          if (out0f) out0f[b * o0_bs + row * ld0 + col] = x;
        }
      }
    }
  }
}

// ---------- small kernels ----------
// transpose+cast: in f32 [R][C] -> out bf16 [Cp][out_ld], out[c][r] = in[r][c], pad 0
__global__ void k_transpose_cast(const float* __restrict__ in, u16* __restrict__ out,
                                 int R, int C, int Cp, int out_ld,
                                 long in_bs, long out_bs) {
  __shared__ float t[32][33];
  long b = blockIdx.z;
  int c0 = blockIdx.x * 32, r0 = blockIdx.y * 32;
  int tx = threadIdx.x, ty = threadIdx.y;
#pragma unroll
  for (int i = 0; i < 32; i += 8) {
    int r = r0 + ty + i, c = c0 + tx;
    t[ty + i][tx] = (r < R && c < C) ? in[b * in_bs + (long)r * C + c] : 0.f;
  }
  __syncthreads();
#pragma unroll
  for (int i = 0; i < 32; i += 8) {
    int c = c0 + ty + i, r = r0 + tx;
    if (c < Cp && r < R)
      out[b * out_bs + (long)c * out_ld + r] = f2bf(t[tx][ty + i]);
  }
}

// cast f32 [R][Cin] -> bf16 [R][Cout] with zero pad
__global__ void k_cast_pad(const float* __restrict__ in, u16* __restrict__ out,
                           int Cin, int Cout, long in_bs, long out_bs) {
  int c = blockIdx.x * 256 + threadIdx.x;
  int r = blockIdx.y;
  long b = blockIdx.z;
  if (c >= Cout) return;
  out[b * out_bs + (long)r * Cout + c] =
      (c < Cin) ? f2bf(in[b * in_bs + (long)r * Cin + c]) : (u16)0;
}

__global__ void k_build_wru(const float* __restrict__ wr_, const float* __restrict__ wu_,
                            u16* __restrict__ wrux, u16* __restrict__ wruh) {
  int k = blockIdx.x * 256 + threadIdx.x;  // 0..511
  int m = blockIdx.y;                      // 0..1023
  if (k >= 512) return;
  const float* src = (m < 512) ? wr_ : wu_;
  int mm = m & 511;
  wrux[m * 512 + k] = f2bf(src[mm * 1024 + k]);
  wruh[m * 512 + k] = f2bf(src[mm * 1024 + 512 + k]);
}

__global__ void k_bias_ru(const float* __restrict__ br_, const float* __restrict__ bu_,
                          float* __restrict__ bias) {
  int i = blockIdx.x * 256 + threadIdx.x;
  if (i < 1024) bias[i] = (i < 512) ? br_[i] : bu_[i - 512];
}

// invZ[b][q] = 1 / sum_nb Zp[b][nb][q]
__global__ void k_invz(const float* __restrict__ Zp, float* __restrict__ invZ) {
  int t = blockIdx.x * 256 + threadIdx.x;
  if (t >= NB * NP) return;
  int b = t / NP, q = t - b * NP;
  const float* base = Zp + (long)b * 49 * NP + q;
  float s = 0.f;
#pragma unroll
  for (int nb = 0; nb < 49; ++nb) s += base[(long)nb * NP];
  invZ[t] = 1.f / s;
}

// memTb[b][q][o] = bf16( sum_{s<2} Ppart[b*2+s][q][o] )   (invZ pre-applied)
__global__ void k_reduce_mem(const float* __restrict__ Ppart, u16* __restrict__ memTb) {
  long t = (long)blockIdx.x * 256 + threadIdx.x;   // f32x4 index
  const long bs = (long)NP * DO_;
  if (t >= (long)NB * bs / 4) return;
  long flat = t * 4;
  int b = (int)(flat / bs);
  long r = flat - (long)b * bs;
  f32x4 s = *(const f32x4*)&Ppart[(long)(b * 2) * bs + r] +
            *(const f32x4*)&Ppart[(long)(b * 2 + 1) * bs + r];
  uint2 pk;
  pk.x = (unsigned)f2bf(s[0]) | ((unsigned)f2bf(s[1]) << 16);
  pk.y = (unsigned)f2bf(s[2]) | ((unsigned)f2bf(s[3]) << 16);
  *(uint2*)&memTb[(long)b * bs + r] = pk;
}

// Qfin [NP][512] f32 -> d_out[b][ch][HW] (first 512 channels)
__global__ void k_out_q(const float* __restrict__ Qfin, float* __restrict__ dout) {
  __shared__ float t[32][33];
  long b = blockIdx.z;
  int q0 = blockIdx.x * 32, ch0 = blockIdx.y * 32;
  int tx = threadIdx.x, ty = threadIdx.y;
#pragma unroll
  for (int i = 0; i < 32; i += 8)
    t[ty + i][tx] = Qfin[b * ((long)NP * 512) + (long)(q0 + ty + i) * 512 + ch0 + tx];
  __syncthreads();
#pragma unroll
  for (int i = 0; i < 32; i += 8) {
    int ch = ch0 + ty + i, q = q0 + tx;
    if (q < HW)
      dout[b * ((long)1024 * HW) + (long)ch * HW + q] = t[tx][ty + i];
  }
}

__global__ void k_copy_q0(const float4* __restrict__ src, float4* __restrict__ dst) {
  int idx = blockIdx.x * 256 + threadIdx.x;
  long b = blockIdx.z;
  const long n4 = (long)DO_ * HW / 4;  // 199680
  if (idx < n4)
    dst[b * ((long)1024 * HW / 4) + n4 + idx] = src[b * n4 + idx];
}

// ---------- host ----------
extern "C" void kernel_launch(void* const* d_in, const int* in_sizes, int n_in,
                              void* d_out, int out_size, void* d_ws, size_t ws_size,
                              hipStream_t stream) {
  const float* m_in  = (const float*)d_in[0];
  const float* m_out = (const float*)d_in[1];
  const float* q_in  = (const float*)d_in[2];
  const float* q_out = (const float*)d_in[3];
  const float* wr    = (const float*)d_in[4];
  const float* br    = (const float*)d_in[5];
  const float* wu    = (const float*)d_in[6];
  const float* bu    = (const float*)d_in[7];
  const float* wc    = (const float*)d_in[8];
  const float* bc    = (const float*)d_in[9];
  float* dout = (float*)d_out;

  // workspace layout (all sizes 256B-multiples)
  char* p = (char*)d_ws;
  size_t off = 0;
  auto alloc = [&](size_t bytes) { void* r = p + off; off += (bytes + 255) & ~(size_t)255; return r; };
  u16*   miT    = (u16*)alloc((size_t)NB * KP * DE * 2);       // [b][k(6272)][d(128)]
  u16*   qiT    = (u16*)alloc((size_t)NB * NP * DE * 2);       // [b][q(1664)][d(128)]
  u16*   Pt     = (u16*)alloc((size_t)NB * NP * KP * 2);       // [b][q][k] = exp(S)
  float* invZ   = (float*)alloc((size_t)NB * NP * 4);
  u16*   moutb  = (u16*)alloc((size_t)NB * DO_ * KP * 2);      // [b][o][k]
  u16*   memTb  = (u16*)alloc((size_t)NB * NP * DO_ * 2);      // [b][q][o] bf16
  // chru,U,XRb contiguous: split-K partials (2*NB*NP*DO_*4 = 27.3MB) alias this
  // 34MB span (all three dead until after k_reduce_mem).
  u16*   chru   = (u16*)alloc((size_t)NB * NP * 1024 * 2);     // [b][q][1024] bf16
  u16*   U      = (u16*)alloc((size_t)NB * NP * DO_ * 2);      // bf16
  u16*   XRb    = (u16*)alloc((size_t)NB * NP * 1024 * 2);
  u16*   XRa    = (u16*)alloc((size_t)NB * NP * 1024 * 2);     // [b][q][x(512)|rh(512)]
  float* Qfin   = (float*)alloc((size_t)NB * NP * DO_ * 4);
  u16*   wrux   = (u16*)alloc((size_t)1024 * 512 * 2);
  u16*   wruh   = (u16*)alloc((size_t)1024 * 512 * 2);
  u16*   wcb    = (u16*)alloc((size_t)512 * 1024 * 2);
  float* biasru = (float*)alloc((size_t)1024 * 4);
  float* Ppart  = (float*)chru;    // [8][NP][DO_] f32, alias
  float* Zp     = (float*)memTb;   // [NB][49][NP] f32, alias (dead before memTb write)
  if (off > ws_size) return;  // workspace too small -> fail visibly

  // --- prep: weights ---
  k_build_wru<<<dim3(2, 1024), 256, 0, stream>>>(wr, wu, wrux, wruh);
  k_cast_pad<<<dim3(4, 512, 1), 256, 0, stream>>>(wc, wcb, 1024, 1024, 0, 0);
  k_bias_ru<<<dim3(4), 256, 0, stream>>>(br, bu, biasru);
  // --- prep: inputs ---
  k_cast_pad<<<dim3(25, 512, NB), 256, 0, stream>>>(
      m_out, moutb, THW, KP, (long)DO_ * THW, (long)DO_ * KP);
  k_transpose_cast<<<dim3(196, 4, NB), dim3(32, 8), 0, stream>>>(
      m_in, miT, DE, THW, KP, DE, (long)DE * THW, (long)KP * DE);
  k_transpose_cast<<<dim3(52, 4, NB), dim3(32, 8), 0, stream>>>(
      q_in, qiT, DE, HW, NP, DE, (long)DE * HW, (long)NP * DE);
  k_transpose_cast<<<dim3(52, 16, NB), dim3(32, 8), 0, stream>>>(
      q_out, XRa, DO_, HW, NP, 1024, (long)DO_ * HW, (long)NP * 1024);

  // --- attention scores: Pt[q,k] = exp(qiT·miT^T / sqrt(De)); Zp row-partials ---
  gemm_bt<0, 1, 128><<<dim3(13, 49, NB), 256, 0, stream>>>(
      qiT, miT, DE, DE, DE, (long)NP * DE, (long)KP * DE,
      Zp, (long)49 * NP, 0, Pt, (long)NP * KP, KP,
      nullptr, 0, nullptr, 0, nullptr, 0, THW, 0.08838834764831845f);
  k_invz<<<dim3(26), 256, 0, stream>>>(Zp, invZ);

  // --- mem (split-K x2, invZ folded): Ppart[z] = (Pt @ moutb^T)*invZ ---
  gemm_bt<5, 2, 64><<<dim3(26, 4, NB * 2), 256, 0, stream>>>(
      Pt, moutb, KP, KP, KP, (long)NP * KP, (long)DO_ * KP,
      Ppart, (long)NP * DO_, DO_, nullptr, 0, 0,
      invZ, NP, nullptr, 0, nullptr, 0, 0, 0.f);
  k_reduce_mem<<<dim3(3328), 256, 0, stream>>>(Ppart, memTb);

  // --- Chru(bf16) = memT @ Wruh^T + [br;bu] ---
  gemm_bt<2, 1, 64><<<dim3(26, 8, NB), 256, 0, stream>>>(
      memTb, wruh, DO_, DO_, DO_, (long)NP * DO_, 0,
      nullptr, 0, 0, chru, (long)NP * 1024, 1024,
      biasru, 0, nullptr, 0, nullptr, 0, 0, 0.f);

  // --- GRU layers ---
  u16* xr[2] = {XRa, XRb};
  for (int l = 0; l < PROP; ++l) {
    u16* cur = xr[l & 1];
    u16* nxt = xr[(l + 1) & 1];
    // gates r,u: sigmoid(X @ Wrux^T + chru); r*mem -> cur cols 512.., u -> U
    gemm_bt<3, 1, 64><<<dim3(26, 8, NB), 256, 0, stream>>>(
        cur, wrux, DO_, 1024, DO_, (long)NP * 1024, 0,
        U, (long)NP * DO_, DO_, cur, (long)NP * 1024, 1024,
        chru, (long)NP * 1024, memTb, (long)NP * DO_, nullptr, 0, 0, 0.f);
    // candidate + update: x' = mem*(1-u) + u*tanh(XR @ wc^T + bc)
    gemm_bt<4, 1, 64><<<dim3(26, 4, NB), 256, 0, stream>>>(
        cur, wcb, 1024, 1024, 1024, (long)NP * 1024, 0,
        (l == PROP - 1) ? (void*)Qfin : nullptr, (long)NP * DO_, DO_,
        nxt, (long)NP * 1024, 1024,
        bc, 0, U, (long)NP * DO_, memTb, (long)NP * DO_, 0, 0.f);
  }

  // --- outputs ---
  k_out_q<<<dim3(49, 16, NB), dim3(32, 8), 0, stream>>>(Qfin, dout);
  k_copy_q0<<<dim3(780, 1, NB), 256, 0, stream>>>((const float4*)q_out, (float4*)dout);
}

// Round 4
// 679.123 us; speedup vs baseline: 1.3394x; 1.0847x over previous
//
#include <hip/hip_runtime.h>
#include <hip/hip_bf16.h>
#include <math.h>

typedef unsigned short u16;
typedef __attribute__((ext_vector_type(8))) short bf16x8;
typedef __attribute__((ext_vector_type(4))) float f32x4;

// ---------- helpers ----------
__device__ __forceinline__ u16 f2bf(float f) {
  union { float f; unsigned u; } x; x.f = f;
  unsigned r = x.u + 0x7fffu + ((x.u >> 16) & 1u);
  return (u16)(r >> 16);
}
__device__ __forceinline__ float bf2f(u16 h) {
  union { unsigned u; float f; } x; x.u = ((unsigned)h) << 16;
  return x.f;
}
__device__ __forceinline__ float sigmf(float x) {
  x = fminf(fmaxf(x, -30.f), 30.f);
  return 1.f / (1.f + __expf(-x));
}
__device__ __forceinline__ float tanh_fast(float x) {
  x = fminf(fmaxf(x, -15.f), 15.f);
  float t = __expf(2.f * x);
  return (t - 1.f) / (t + 1.f);
}

// ---------- problem constants ----------
#define NB 4
#define DE 128
#define DO_ 512
#define HW 1560
#define THW 6240
#define NP 1664   // HW padded to 13*128
#define KP 6272   // THW padded to 49*128
#define PROP 5

// ---------- generic bf16 GEMM:  C[M,N] = A[M,K] * Bt[N,K]^T ----------
// A row-major [M,K], Bt row-major [N,K]. Tile BMT x 128, K-step BKT,
// 4 waves, 16x16x32 bf16 MFMA, global_load_lds staging, 2-phase double buffer
// (stage(t+1) issued before compute(t); barrier vmcnt(0) drain syncs).
template<int MODE, int BMT, int BKT>
__global__ __launch_bounds__(256)
void gemm_bt(const u16* __restrict__ A, const u16* __restrict__ Bt,
             int K, int lda, int ldb, long a_bs, long b_bs,
             void* __restrict__ out0v, long o0_bs, int ld0,
             u16* __restrict__ out1, long o1_bs, int ld1,
             const void* __restrict__ e0v, long e0_bs,
             const void* __restrict__ e1v, long e1_bs,
             const void* __restrict__ e2v, long e2_bs,
             int nvalid, float scale)
{
  constexpr int WR = BMT / 64;        // wave rows (2 or 1)
  constexpr int WC = 4 / WR;          // wave cols (2 or 4)
  constexpr int NF = 8 / WC;          // 16-wide n-frags per wave
  constexpr int KK = BKT / 32;        // k-subtiles per step
  constexpr int ASLOT = BMT * BKT / 8;
  constexpr int BSLOT = 128 * BKT / 8;
  constexpr int NISS = (ASLOT + BSLOT) / 256;
  constexpr int RSH = (BMT == 128) ? 7 : 6;
  __shared__ u16 lds[2][ASLOT + BSLOT][8];

  const int tid = threadIdx.x;
  const int wave = tid >> 6, lane = tid & 63;
  const int kg = lane >> 4, lr = lane & 15;
  const int wrw = wave / WC, wcw = wave % WC;
  const long b = blockIdx.z;
  const int m0 = blockIdx.x * BMT, n0 = blockIdx.y * 128;
  A += b * a_bs; Bt += b * b_bs;

  float* out0f = (float*)out0v;
  u16* out0h = (u16*)out0v;
  const float* e0f = (const float*)e0v;
  const u16* e0h = (const u16*)e0v;
  const u16* e1h = (const u16*)e1v;
  const u16* e2h = (const u16*)e2v;

  auto stage = [&](int buf, int kt) {
#pragma unroll
    for (int i = 0; i < NISS; ++i) {
      int s = tid + 256 * i;
      const u16* src;
      if (s < ASLOT) {
        int row = s & (BMT - 1), g = s >> RSH;
        src = A + (long)(m0 + row) * lda + kt + g * 8;
      } else {
        int s2 = s - ASLOT;
        int row = s2 & 127, g = s2 >> 7;
        src = Bt + (long)(n0 + row) * ldb + kt + g * 8;
      }
      __builtin_amdgcn_global_load_lds(
          (const __attribute__((address_space(1))) void*)src,
          (__attribute__((address_space(3))) void*)&lds[buf][wave * 64 + 256 * i][0],
          16, 0, 0);
    }
  };

  f32x4 acc[4][NF];
#pragma unroll
  for (int m = 0; m < 4; ++m)
#pragma unroll
    for (int n = 0; n < NF; ++n) acc[m][n] = (f32x4){0.f, 0.f, 0.f, 0.f};

  const int nt = K / BKT;
  stage(0, 0);
  __syncthreads();
  for (int t = 0; t < nt; ++t) {
    int cur = t & 1;
    if (t + 1 < nt) stage(cur ^ 1, (t + 1) * BKT);
    bf16x8 af[KK][4], bfr[KK][NF];
#pragma unroll
    for (int kk = 0; kk < KK; ++kk) {
#pragma unroll
      for (int m = 0; m < 4; ++m)
        af[kk][m] = *(const bf16x8*)&lds[cur][(kk * 4 + kg) * BMT + wrw * 64 + m * 16 + lr][0];
#pragma unroll
      for (int n = 0; n < NF; ++n)
        bfr[kk][n] = *(const bf16x8*)&lds[cur][ASLOT + (kk * 4 + kg) * 128 + (wcw * NF + n) * 16 + lr][0];
    }
#pragma unroll
    for (int kk = 0; kk < KK; ++kk)
#pragma unroll
      for (int m = 0; m < 4; ++m)
#pragma unroll
        for (int n = 0; n < NF; ++n)
          acc[m][n] = __builtin_amdgcn_mfma_f32_16x16x32_bf16(af[kk][m], bfr[kk][n], acc[m][n], 0, 0, 0);
    __syncthreads();
  }

  // frag elem j -> row = m0+wrw*64+m*16+kg*4+j, col = n0+(wcw*NF+n)*16+lr
  if constexpr (MODE == 0) {
    // scores -> Pt = exp(S*scale), zero padded k; also per-block row-sums Zp
    float rs[4][4];
#pragma unroll
    for (int m = 0; m < 4; ++m)
#pragma unroll
      for (int j = 0; j < 4; ++j) rs[m][j] = 0.f;
#pragma unroll
    for (int m = 0; m < 4; ++m) {
      int rloc = wrw * 64 + m * 16 + kg * 4;
#pragma unroll
      for (int n = 0; n < NF; ++n) {
        int col = n0 + (wcw * NF + n) * 16 + lr;
#pragma unroll
        for (int j = 0; j < 4; ++j) {
          long row = m0 + rloc + j;
          float p = __expf(acc[m][n][j] * scale);
          bool valid = (col < nvalid);
          out1[b * o1_bs + row * ld1 + col] = valid ? f2bf(p) : (u16)0;
          rs[m][j] += valid ? p : 0.f;
        }
      }
    }
#pragma unroll
    for (int m = 0; m < 4; ++m)
#pragma unroll
      for (int j = 0; j < 4; ++j) {
#pragma unroll
        for (int msk = 1; msk < 16; msk <<= 1)
          rs[m][j] += __shfl_xor(rs[m][j], msk, 64);
      }
    float* zbuf = (float*)lds;  // 2*128 floats
    if (lr == 0) {
#pragma unroll
      for (int m = 0; m < 4; ++m)
#pragma unroll
        for (int j = 0; j < 4; ++j)
          zbuf[wcw * 128 + wrw * 64 + m * 16 + kg * 4 + j] = rs[m][j];
    }
    __syncthreads();
    if (tid < 128)
      out0f[b * o0_bs + (long)blockIdx.y * NP + (m0 + tid)] = zbuf[tid] + zbuf[128 + tid];
    return;
  }

#pragma unroll
  for (int m = 0; m < 4; ++m) {
    int rloc = wrw * 64 + m * 16 + kg * 4;
#pragma unroll
    for (int n = 0; n < NF; ++n) {
      int col = n0 + (wcw * NF + n) * 16 + lr;
#pragma unroll
      for (int j = 0; j < 4; ++j) {
        long row = m0 + rloc + j;
        float v = acc[m][n][j];
        if constexpr (MODE == 2) {        // Chru(bf16) = memT @ Wruh^T + bias_ru
          out1[b * o1_bs + row * ld1 + col] = f2bf(v + e0f[col]);
        } else if constexpr (MODE == 3) { // gates r,u (chru bf16, mem bf16)
          float gt = sigmf(v + bf2f(e0h[b * e0_bs + row * 1024 + col]));
          if (col < 512)                  // r -> RH = r*mem into XR cols 512..1023
            out1[b * o1_bs + row * ld1 + 512 + col] =
                f2bf(gt * bf2f(e1h[b * e1_bs + row * 512 + col]));
          else                            // u -> U (bf16)
            out0h[b * o0_bs + row * ld0 + (col - 512)] = f2bf(gt);
        } else if constexpr (MODE == 4) { // candidate + GRU update
          float cg = tanh_fast(v + e0f[col]);
          float u = bf2f(e1h[b * e1_bs + row * 512 + col]);
          float mm = bf2f(e2h[b * e2_bs + row * 512 + col]);
          float x = mm * (1.f - u) + u * cg;
          out1[b * o1_bs + row * ld1 + col] = f2bf(x);
          if (out0f) out0f[b * o0_bs + row * ld0 + col] = x;
        }
      }
    }
  }
}

// ---------- mem GEMM: Ppart[bz] = Pt(chunk) @ moutb^T, BN=512 full-N ----------
// 416 blocks: bid&7 -> XCD gets (b,z) pair; A (Pt) LDS double-buffered;
// B (moutb) streamed global->reg from L2 with one-step register prefetch.
__global__ __launch_bounds__(256, 2)
void gemm_pv(const u16* __restrict__ Pt, const u16* __restrict__ moutb,
             u16* __restrict__ Ppart)
{
  const int bid = blockIdx.x;           // 0..415
  const int xcd = bid & 7, j = bid >> 3; // j 0..51
  const int bz = 2 * xcd + (j >= 26);
  const int mb = (j >= 26) ? (j - 26) : j;
  const int b = bz >> 2, z = bz & 3;
  const int m0 = mb * 64;
  const int k0 = z * 1568;              // 49 steps of 32

  const u16* A = Pt + (long)b * NP * KP;
  const u16* B0;
  {
    const u16* Bb = moutb + (long)b * DO_ * KP;
    B0 = Bb + (long)((threadIdx.x >> 6) * 128 + (threadIdx.x & 15)) * KP + ((threadIdx.x & 63) >> 4) * 8;
  }

  __shared__ u16 lds[2][2048];          // [buf][g(4)][row(64)][8]
  const int tid = threadIdx.x;
  const int wave = tid >> 6, lane = tid & 63;
  const int kg = lane >> 4, lr = lane & 15;

  auto stage = [&](int buf, int kt) {
    int row = tid & 63, g = tid >> 6;
    const u16* src = A + (long)(m0 + row) * KP + kt + g * 8;
    __builtin_amdgcn_global_load_lds(
        (const __attribute__((address_space(1))) void*)src,
        (__attribute__((address_space(3))) void*)&lds[buf][(wave * 64) * 8],
        16, 0, 0);
  };

  f32x4 acc[4][8];
#pragma unroll
  for (int m = 0; m < 4; ++m)
#pragma unroll
    for (int n = 0; n < 8; ++n) acc[m][n] = (f32x4){0.f, 0.f, 0.f, 0.f};

  bf16x8 bra[8], brb[8];
#pragma unroll
  for (int n = 0; n < 8; ++n)
    bra[n] = *(const bf16x8*)&B0[(long)n * 16 * KP + k0];
  stage(0, k0);
  __syncthreads();

#define PV_STEP(BU, BL, T, CUR)                                                  \
  {                                                                              \
    if ((T) + 1 < 49) {                                                          \
      int ktn = k0 + ((T) + 1) * 32;                                             \
      _Pragma("unroll") for (int n = 0; n < 8; ++n)                              \
          BL[n] = *(const bf16x8*)&B0[(long)n * 16 * KP + ktn];                  \
      stage((CUR) ^ 1, ktn);                                                     \
    }                                                                            \
    bf16x8 af[4];                                                                \
    _Pragma("unroll") for (int m = 0; m < 4; ++m)                                \
        af[m] = *(const bf16x8*)&lds[CUR][(kg * 64 + m * 16 + lr) * 8];          \
    _Pragma("unroll") for (int m = 0; m < 4; ++m)                                \
        _Pragma("unroll") for (int n = 0; n < 8; ++n)                            \
            acc[m][n] = __builtin_amdgcn_mfma_f32_16x16x32_bf16(af[m], BU[n],    \
                                                                acc[m][n], 0, 0, 0); \
    __syncthreads();                                                             \
  }

  for (int tp = 0; tp < 24; ++tp) {
    PV_STEP(bra, brb, 2 * tp, 0);
    PV_STEP(brb, bra, 2 * tp + 1, 1);
  }
  PV_STEP(bra, brb, 48, 0);
#undef PV_STEP

  // write bf16 partial tile [64][512]
  u16* out = Ppart + (long)bz * NP * DO_;
#pragma unroll
  for (int m = 0; m < 4; ++m) {
#pragma unroll
    for (int n = 0; n < 8; ++n) {
      int col = wave * 128 + n * 16 + lr;
#pragma unroll
      for (int j = 0; j < 4; ++j) {
        int row = m0 + m * 16 + kg * 4 + j;
        out[(long)row * DO_ + col] = f2bf(acc[m][n][j]);
      }
    }
  }
}

// ---------- small kernels ----------
// transpose+cast: in f32 [R][C] -> out bf16 [Cp][out_ld], out[c][r] = in[r][c], pad 0
__global__ void k_transpose_cast(const float* __restrict__ in, u16* __restrict__ out,
                                 int R, int C, int Cp, int out_ld,
                                 long in_bs, long out_bs) {
  __shared__ float t[32][33];
  long b = blockIdx.z;
  int c0 = blockIdx.x * 32, r0 = blockIdx.y * 32;
  int tx = threadIdx.x, ty = threadIdx.y;
#pragma unroll
  for (int i = 0; i < 32; i += 8) {
    int r = r0 + ty + i, c = c0 + tx;
    t[ty + i][tx] = (r < R && c < C) ? in[b * in_bs + (long)r * C + c] : 0.f;
  }
  __syncthreads();
#pragma unroll
  for (int i = 0; i < 32; i += 8) {
    int c = c0 + ty + i, r = r0 + tx;
    if (c < Cp && r < R)
      out[b * out_bs + (long)c * out_ld + r] = f2bf(t[tx][ty + i]);
  }
}

// cast f32 [R][Cin] -> bf16 [R][Cout] with zero pad
__global__ void k_cast_pad(const float* __restrict__ in, u16* __restrict__ out,
                           int Cin, int Cout, long in_bs, long out_bs) {
  int c = blockIdx.x * 256 + threadIdx.x;
  int r = blockIdx.y;
  long b = blockIdx.z;
  if (c >= Cout) return;
  out[b * out_bs + (long)r * Cout + c] =
      (c < Cin) ? f2bf(in[b * in_bs + (long)r * Cin + c]) : (u16)0;
}

__global__ void k_build_wru(const float* __restrict__ wr_, const float* __restrict__ wu_,
                            u16* __restrict__ wrux, u16* __restrict__ wruh) {
  int k = blockIdx.x * 256 + threadIdx.x;  // 0..511
  int m = blockIdx.y;                      // 0..1023
  if (k >= 512) return;
  const float* src = (m < 512) ? wr_ : wu_;
  int mm = m & 511;
  wrux[m * 512 + k] = f2bf(src[mm * 1024 + k]);
  wruh[m * 512 + k] = f2bf(src[mm * 1024 + 512 + k]);
}

__global__ void k_bias_ru(const float* __restrict__ br_, const float* __restrict__ bu_,
                          float* __restrict__ bias) {
  int i = blockIdx.x * 256 + threadIdx.x;
  if (i < 1024) bias[i] = (i < 512) ? br_[i] : bu_[i - 512];
}

// invZ[b][q] = 1 / sum_nb Zp[b][nb][q]
__global__ void k_invz(const float* __restrict__ Zp, float* __restrict__ invZ) {
  int t = blockIdx.x * 256 + threadIdx.x;
  if (t >= NB * NP) return;
  int b = t / NP, q = t - b * NP;
  const float* base = Zp + (long)b * 49 * NP + q;
  float s = 0.f;
#pragma unroll
  for (int nb = 0; nb < 49; ++nb) s += base[(long)nb * NP];
  invZ[t] = 1.f / s;
}

// memTb[b][q][o] = bf16( invZ[b][q] * sum_{z<4} Ppart[b*4+z][q][o] )
__global__ void k_reduce_mem(const u16* __restrict__ Ppart, const float* __restrict__ invZ,
                             u16* __restrict__ memTb) {
  long t = (long)blockIdx.x * 256 + threadIdx.x;   // uint4 index (8 bf16)
  const long bs = (long)NP * DO_;
  if (t >= (long)NB * bs / 8) return;
  long flat = t * 8;
  int b = (int)(flat / bs);
  long r = flat - (long)b * bs;
  int q = (int)(r / DO_);
  float s[8];
#pragma unroll
  for (int e = 0; e < 8; ++e) s[e] = 0.f;
#pragma unroll
  for (int z = 0; z < 4; ++z) {
    uint4 v = *(const uint4*)&Ppart[(long)(b * 4 + z) * bs + r];
    s[0] += bf2f((u16)(v.x & 0xffff)); s[1] += bf2f((u16)(v.x >> 16));
    s[2] += bf2f((u16)(v.y & 0xffff)); s[3] += bf2f((u16)(v.y >> 16));
    s[4] += bf2f((u16)(v.z & 0xffff)); s[5] += bf2f((u16)(v.z >> 16));
    s[6] += bf2f((u16)(v.w & 0xffff)); s[7] += bf2f((u16)(v.w >> 16));
  }
  float iz = invZ[b * NP + q];
  uint4 o;
  o.x = (unsigned)f2bf(s[0] * iz) | ((unsigned)f2bf(s[1] * iz) << 16);
  o.y = (unsigned)f2bf(s[2] * iz) | ((unsigned)f2bf(s[3] * iz) << 16);
  o.z = (unsigned)f2bf(s[4] * iz) | ((unsigned)f2bf(s[5] * iz) << 16);
  o.w = (unsigned)f2bf(s[6] * iz) | ((unsigned)f2bf(s[7] * iz) << 16);
  *(uint4*)&memTb[(long)b * bs + r] = o;
}

// Qfin [NP][512] f32 -> d_out[b][ch][HW] (first 512 channels)
__global__ void k_out_q(const float* __restrict__ Qfin, float* __restrict__ dout) {
  __shared__ float t[32][33];
  long b = blockIdx.z;
  int q0 = blockIdx.x * 32, ch0 = blockIdx.y * 32;
  int tx = threadIdx.x, ty = threadIdx.y;
#pragma unroll
  for (int i = 0; i < 32; i += 8)
    t[ty + i][tx] = Qfin[b * ((long)NP * 512) + (long)(q0 + ty + i) * 512 + ch0 + tx];
  __syncthreads();
#pragma unroll
  for (int i = 0; i < 32; i += 8) {
    int ch = ch0 + ty + i, q = q0 + tx;
    if (q < HW)
      dout[b * ((long)1024 * HW) + (long)ch * HW + q] = t[tx][ty + i];
  }
}

__global__ void k_copy_q0(const float4* __restrict__ src, float4* __restrict__ dst) {
  int idx = blockIdx.x * 256 + threadIdx.x;
  long b = blockIdx.z;
  const long n4 = (long)DO_ * HW / 4;  // 199680
  if (idx < n4)
    dst[b * ((long)1024 * HW / 4) + n4 + idx] = src[b * n4 + idx];
}

// ---------- host ----------
extern "C" void kernel_launch(void* const* d_in, const int* in_sizes, int n_in,
                              void* d_out, int out_size, void* d_ws, size_t ws_size,
                              hipStream_t stream) {
  const float* m_in  = (const float*)d_in[0];
  const float* m_out = (const float*)d_in[1];
  const float* q_in  = (const float*)d_in[2];
  const float* q_out = (const float*)d_in[3];
  const float* wr    = (const float*)d_in[4];
  const float* br    = (const float*)d_in[5];
  const float* wu    = (const float*)d_in[6];
  const float* bu    = (const float*)d_in[7];
  const float* wc    = (const float*)d_in[8];
  const float* bc    = (const float*)d_in[9];
  float* dout = (float*)d_out;

  // workspace layout (all sizes 256B-multiples)
  char* p = (char*)d_ws;
  size_t off = 0;
  auto alloc = [&](size_t bytes) { void* r = p + off; off += (bytes + 255) & ~(size_t)255; return r; };
  u16*   miT    = (u16*)alloc((size_t)NB * KP * DE * 2);       // [b][k(6272)][d(128)]
  u16*   qiT    = (u16*)alloc((size_t)NB * NP * DE * 2);       // [b][q(1664)][d(128)]
  u16*   Pt     = (u16*)alloc((size_t)NB * NP * KP * 2);       // [b][q][k] = exp(S)
  float* invZ   = (float*)alloc((size_t)NB * NP * 4);
  u16*   moutb  = (u16*)alloc((size_t)NB * DO_ * KP * 2);      // [b][o][k]
  u16*   memTb  = (u16*)alloc((size_t)NB * NP * DO_ * 2);      // [b][q][o] bf16
  // chru,U,XRb contiguous: bf16 partials (16*NP*DO_*2 = 27.3MB) alias this
  // 34MB span (all three dead until after k_reduce_mem).
  u16*   chru   = (u16*)alloc((size_t)NB * NP * 1024 * 2);     // [b][q][1024] bf16
  u16*   U      = (u16*)alloc((size_t)NB * NP * DO_ * 2);      // bf16
  u16*   XRb    = (u16*)alloc((size_t)NB * NP * 1024 * 2);
  u16*   XRa    = (u16*)alloc((size_t)NB * NP * 1024 * 2);     // [b][q][x(512)|rh(512)]
  float* Qfin   = (float*)alloc((size_t)NB * NP * DO_ * 4);
  u16*   wrux   = (u16*)alloc((size_t)1024 * 512 * 2);
  u16*   wruh   = (u16*)alloc((size_t)1024 * 512 * 2);
  u16*   wcb    = (u16*)alloc((size_t)512 * 1024 * 2);
  float* biasru = (float*)alloc((size_t)1024 * 4);
  u16*   Ppart  = (u16*)chru;      // [16][NP][DO_] bf16, alias
  float* Zp     = (float*)memTb;   // [NB][49][NP] f32, alias (dead before memTb write)
  if (off > ws_size) return;  // workspace too small -> fail visibly

  // --- prep: weights ---
  k_build_wru<<<dim3(2, 1024), 256, 0, stream>>>(wr, wu, wrux, wruh);
  k_cast_pad<<<dim3(4, 512, 1), 256, 0, stream>>>(wc, wcb, 1024, 1024, 0, 0);
  k_bias_ru<<<dim3(4), 256, 0, stream>>>(br, bu, biasru);
  // --- prep: inputs ---
  k_cast_pad<<<dim3(25, 512, NB), 256, 0, stream>>>(
      m_out, moutb, THW, KP, (long)DO_ * THW, (long)DO_ * KP);
  k_transpose_cast<<<dim3(196, 4, NB), dim3(32, 8), 0, stream>>>(
      m_in, miT, DE, THW, KP, DE, (long)DE * THW, (long)KP * DE);
  k_transpose_cast<<<dim3(52, 4, NB), dim3(32, 8), 0, stream>>>(
      q_in, qiT, DE, HW, NP, DE, (long)DE * HW, (long)NP * DE);
  k_transpose_cast<<<dim3(52, 16, NB), dim3(32, 8), 0, stream>>>(
      q_out, XRa, DO_, HW, NP, 1024, (long)DO_ * HW, (long)NP * 1024);

  // --- attention scores: Pt[q,k] = exp(qiT·miT^T / sqrt(De)); Zp row-partials ---
  gemm_bt<0, 128, 32><<<dim3(13, 49, NB), 256, 0, stream>>>(
      qiT, miT, DE, DE, DE, (long)NP * DE, (long)KP * DE,
      Zp, (long)49 * NP, 0, Pt, (long)NP * KP, KP,
      nullptr, 0, nullptr, 0, nullptr, 0, THW, 0.08838834764831845f);
  k_invz<<<dim3(26), 256, 0, stream>>>(Zp, invZ);

  // --- mem: Ppart[bz] = Pt(chunk) @ moutb^T (BN=512, split-K x4) ---
  gemm_pv<<<dim3(416), 256, 0, stream>>>(Pt, moutb, Ppart);
  k_reduce_mem<<<dim3(1664), 256, 0, stream>>>(Ppart, invZ, memTb);

  // --- Chru(bf16) = memT @ Wruh^T + [br;bu] ---
  gemm_bt<2, 64, 64><<<dim3(26, 8, NB), 256, 0, stream>>>(
      memTb, wruh, DO_, DO_, DO_, (long)NP * DO_, 0,
      nullptr, 0, 0, chru, (long)NP * 1024, 1024,
      biasru, 0, nullptr, 0, nullptr, 0, 0, 0.f);

  // --- GRU layers ---
  u16* xr[2] = {XRa, XRb};
  for (int l = 0; l < PROP; ++l) {
    u16* cur = xr[l & 1];
    u16* nxt = xr[(l + 1) & 1];
    // gates r,u: sigmoid(X @ Wrux^T + chru); r*mem -> cur cols 512.., u -> U
    gemm_bt<3, 64, 64><<<dim3(26, 8, NB), 256, 0, stream>>>(
        cur, wrux, DO_, 1024, DO_, (long)NP * 1024, 0,
        U, (long)NP * DO_, DO_, cur, (long)NP * 1024, 1024,
        chru, (long)NP * 1024, memTb, (long)NP * DO_, nullptr, 0, 0, 0.f);
    // candidate + update: x' = mem*(1-u) + u*tanh(XR @ wc^T + bc)
    gemm_bt<4, 64, 64><<<dim3(26, 4, NB), 256, 0, stream>>>(
        cur, wcb, 1024, 1024, 1024, (long)NP * 1024, 0,
        (l == PROP - 1) ? (void*)Qfin : nullptr, (long)NP * DO_, DO_,
        nxt, (long)NP * 1024, 1024,
        bc, 0, U, (long)NP * DO_, memTb, (long)NP * DO_, 0, 0.f);
  }

  // --- outputs ---
  k_out_q<<<dim3(49, 16, NB), dim3(32, 8), 0, stream>>>(Qfin, dout);
  k_copy_q0<<<dim3(780, 1, NB), 256, 0, stream>>>((const float4*)q_out, (float4*)dout);
}